// Round 11
// baseline (221.250 us; speedup 1.0000x reference)
//
#include <hip/hip_runtime.h>
#include <hip/hip_cooperative_groups.h>
#include <utility>

namespace cg = cooperative_groups;

#define DIM 2048
#define NQ 11
#define NROT 88
#define BSZ 64
#define NT 8
#define NPC 4   // DEGREE+1

#if __has_builtin(__builtin_amdgcn_permlane16_swap)
#define HAVE_PL16 1
#else
#define HAVE_PL16 0
#endif
#if __has_builtin(__builtin_amdgcn_permlane32_swap)
#define HAVE_PL32 1
#else
#define HAVE_PL32 0
#endif

// ---------------------------------------------------------------------------
// Compile-time gate schedule. Gate G in [0,88); wire w <-> state bit 10-w.
// ---------------------------------------------------------------------------
constexpr int g_type(int G) {
    int j = G % 44;
    return (j < 11 || (j >= 22 && j < 33)) ? 0 : 1;   // 0=RY, 1=CRX
}
constexpr int g_pt(int G) {
    int j = G % 44;
    if (j < 11) return 10 - j;
    if (j < 22) { int i = 21 - j; int tw = (i + 1 == NQ) ? 0 : i + 1; return 10 - tw; }
    if (j < 33) return 10 - (j - 22);
    if (j == 33) return 1;
    int i = j - 34; int tw = (i + 10) % NQ; return 10 - tw;
}
constexpr int g_pcb(int G) {
    int j = G % 44;
    if (j >= 11 && j < 22) { int i = 21 - j; return 10 - i; }
    if (j == 33) return 0;
    if (j >= 34) { int i = j - 34; return 10 - i; }
    return -1;  // RY
}
constexpr bool use_sum_tier(int lb) {
    return (lb == 4 && HAVE_PL16) || (lb == 5 && HAVE_PL32);
}

// Transposed layout B: swap amp bits (1,2,3,4) <-> (7,8,9,10); 0,5,6 fixed.
constexpr int tmap(int b) {
    if (b >= 1 && b <= 4) return b + 6;
    if (b >= 7 && b <= 10) return b - 6;
    return b;
}

// ---------------------------------------------------------------------------
// Per-layer op schedule: 50 ops = 44 gates + 6 transposes (r9/r10-proven).
// ---------------------------------------------------------------------------
constexpr int lop_j(int k) {
    if (k < 7)  return 4 + k;            // RY1 targets 6..0            [A]
    if (k == 7) return -1;               // T par0 -> B
    if (k < 12) return k - 8;            // RY1 targets 10,9,8,7        [B]
    if (k == 12) return 11;              // chainA idx0 (c0,t10)        [B]
    if (k == 13) return -1;              // T par1 -> A
    if (k < 21) return 12 + (k - 14);    // chainA idx1..7 (t0..t6)     [A]
    if (k == 21) return -1;              // T par0 -> B
    if (k < 25) return 19 + (k - 22);    // chainA idx8..10 (t7,t8,t9)  [B]
    if (k < 29) return 22 + (k - 25);    // RY2 targets 10,9,8,7        [B]
    if (k == 29) return 26;              // RY2 t6                      [B]
    if (k == 30) return 27;              // RY2 t5                      [B]
    if (k == 31) return 32;              // RY2 t0                      [B]
    if (k == 32) return -1;              // T par1 -> A
    if (k < 37) return 28 + (k - 33);    // RY2 targets 4,3,2,1         [A]
    if (k == 37) return 33;              // chainB idx0 (c0,t1)         [A]
    if (k == 38) return 34;              // chainB idx1 (c10,t0)        [A]
    if (k == 39) return -1;              // T par0 -> B
    if (k < 46) return 35 + (k - 40);    // chainB idx2..7              [B]
    if (k == 46) return -1;              // T par1 -> A
    return 41 + (k - 47);                // chainB idx8..10 (t4,t3,t2)  [A]
}
constexpr bool lop_B(int k) {
    return (k >= 8 && k <= 12) || (k >= 22 && k <= 31) || (k >= 40 && k <= 45);
}
constexpr int lop_tpar(int k) { return (k == 7 || k == 21 || k == 39) ? 0 : 1; }

// ---------------------------------------------------------------------------
// Wave-uniform trig fetch via readlane.
// ---------------------------------------------------------------------------
template<int G>
__device__ __forceinline__ void get_cs(float c0, float s0, float c1, float s1,
                                       float& c, float& s) {
    if constexpr (G < 64) {
        c = __int_as_float(__builtin_amdgcn_readlane(__float_as_int(c0), G));
        s = __int_as_float(__builtin_amdgcn_readlane(__float_as_int(s0), G));
    } else {
        c = __int_as_float(__builtin_amdgcn_readlane(__float_as_int(c1), G - 64));
        s = __int_as_float(__builtin_amdgcn_readlane(__float_as_int(s1), G - 64));
    }
}

// ---------------------------------------------------------------------------
// Lane exchange across tid bit LB — PARTNER form.
// ---------------------------------------------------------------------------
template<int LB>
__device__ __forceinline__ float lxp(float x) {
    if constexpr (LB == 0) {
        return __int_as_float(__builtin_amdgcn_update_dpp(
            __float_as_int(x), __float_as_int(x), 0xB1, 0xF, 0xF, true)); // xor1
    } else if constexpr (LB == 1) {
        return __int_as_float(__builtin_amdgcn_update_dpp(
            __float_as_int(x), __float_as_int(x), 0x4E, 0xF, 0xF, true)); // xor2
    } else if constexpr (LB == 2) {
        return __int_as_float(__builtin_amdgcn_ds_swizzle(__float_as_int(x), 0x101F)); // xor4
    } else if constexpr (LB == 3) {
        return __int_as_float(__builtin_amdgcn_update_dpp(
            __float_as_int(x), __float_as_int(x), 0x128, 0xF, 0xF, true)); // row_ror:8 = xor8
    } else if constexpr (LB == 4) {
        return __int_as_float(__builtin_amdgcn_ds_swizzle(__float_as_int(x), 0x401F)); // xor16
    } else {
        return __shfl_xor(x, 32, 64);                                                  // xor32
    }
}

// SUM form: returns own + partner (order-immune to permlane*_swap ordering).
template<int LB>
__device__ __forceinline__ float lxsum(float x) {
#if HAVE_PL16
    if constexpr (LB == 4) {
        unsigned u = __float_as_uint(x);
        auto r = __builtin_amdgcn_permlane16_swap(u, u, false, false);
        return __uint_as_float(r[0]) + __uint_as_float(r[1]);
    }
#endif
#if HAVE_PL32
    if constexpr (LB == 5) {
        unsigned u = __float_as_uint(x);
        auto r = __builtin_amdgcn_permlane32_swap(u, u, false, false);
        return __uint_as_float(r[0]) + __uint_as_float(r[1]);
    }
#endif
    return x + lxp<LB>(x);
}

// ---------------------------------------------------------------------------
// Layout: 1024 threads, thread tid holds amps a = 2*tid + e, e in {0,1}.
//   amp bits: 0=e, 1..6=lane(tid 0..5), 7..10=block(tid 6..9)
// ---------------------------------------------------------------------------
template<int G, bool PB>
__device__ __forceinline__ void apply_gate(float2& R, float2& I,
    float c0, float s0, float c1, float s1, const int tid)
{
    constexpr int type = g_type(G);
    constexpr int pt   = PB ? tmap(g_pt(G)) : g_pt(G);
    constexpr int pcb0 = g_pcb(G);
    constexpr int pcb  = (pcb0 < 0) ? -1 : (PB ? tmap(pcb0) : pcb0);
    static_assert(pt <= 6, "block-bit target must run in transposed layout");
    float c, s;
    get_cs<G>(c0, s0, c1, s1, c, s);

    if constexpr (pt == 0) {
        if constexpr (type == 0) {
            float rx = R.x, ry = R.y, ix = I.x, iy = I.y;
            R.x = c*rx - s*ry;  R.y = s*rx + c*ry;
            I.x = c*ix - s*iy;  I.y = s*ix + c*iy;
        } else {
            const bool ctrl = (tid >> (pcb - 1)) & 1;
            if (ctrl) {
                float rx = R.x, ry = R.y, ix = I.x, iy = I.y;
                R.x = c*rx + s*iy;   I.x = c*ix - s*ry;
                R.y = c*ry + s*ix;   I.y = c*iy - s*rx;
            }
        }
    } else {
        constexpr int lb = pt - 1;
        if constexpr (use_sum_tier(lb)) {
            if constexpr (type == 0) {
                const float sg = ((tid >> lb) & 1) ? s : -s;
                const float k1 = c - sg;
                float srx = lxsum<lb>(R.x), sry = lxsum<lb>(R.y);
                float six = lxsum<lb>(I.x), siy = lxsum<lb>(I.y);
                R.x = k1*R.x + sg*srx;  R.y = k1*R.y + sg*sry;
                I.x = k1*I.x + sg*six;  I.y = k1*I.y + sg*siy;
            } else if constexpr (pcb == 0) {
                float sry = lxsum<lb>(R.y), siy = lxsum<lb>(I.y);
                float ry = R.y, iy = I.y;
                R.y = c*ry - s*iy + s*siy;
                I.y = c*iy + s*ry - s*sry;
            } else {
                const bool ctrl = (tid >> (pcb - 1)) & 1;
                if (ctrl) {
                    float srx = lxsum<lb>(R.x), sry = lxsum<lb>(R.y);
                    float six = lxsum<lb>(I.x), siy = lxsum<lb>(I.y);
                    float rx = R.x, ry = R.y, ix = I.x, iy = I.y;
                    R.x = c*rx - s*ix + s*six;  R.y = c*ry - s*iy + s*siy;
                    I.x = c*ix + s*rx - s*srx;  I.y = c*iy + s*ry - s*sry;
                }
            }
        } else {
            if constexpr (type == 0) {
                const float sg = ((tid >> lb) & 1) ? s : -s;
                float prx = lxp<lb>(R.x), pry = lxp<lb>(R.y);
                float pix = lxp<lb>(I.x), piy = lxp<lb>(I.y);
                R.x = c*R.x + sg*prx;  R.y = c*R.y + sg*pry;
                I.x = c*I.x + sg*pix;  I.y = c*I.y + sg*piy;
            } else if constexpr (pcb == 0) {
                float pry = lxp<lb>(R.y), piy = lxp<lb>(I.y);
                R.y = c*R.y + s*piy;
                I.y = c*I.y - s*pry;
            } else {
                const bool ctrl = (tid >> (pcb - 1)) & 1;
                if (ctrl) {
                    float prx = lxp<lb>(R.x), pry = lxp<lb>(R.y);
                    float pix = lxp<lb>(I.x), piy = lxp<lb>(I.y);
                    R.x = c*R.x + s*pix;  R.y = c*R.y + s*piy;
                    I.x = c*I.x - s*prx;  I.y = c*I.y - s*pry;
                }
            }
        }
    }
}

// ---------------------------------------------------------------------------
// Whole-payload transpose: swap tid bits (0,1,2,3) <-> (6,7,8,9) via LDS.
// ---------------------------------------------------------------------------
__device__ __forceinline__ int swz16(int s) { return s ^ ((s >> 6) & 15); }

template<int PAR>
__device__ __forceinline__ void transpose_swap(float2& R, float2& I,
    float4* __restrict__ exbuf, const int tid)
{
    float4* buf = exbuf + PAR * 1024;
    const int lo = tid & 15;
    const int hi = (tid >> 6) & 15;
    const int q = (tid & 0x030) | hi | (lo << 6);
    buf[swz16(tid)] = make_float4(R.x, R.y, I.x, I.y);
    __syncthreads();
    float4 v = buf[swz16(q)];
    R = make_float2(v.x, v.y);
    I = make_float2(v.z, v.w);
    // no trailing barrier: parity buffer reused 2 transposes later; the
    // intervening transpose's barrier orders those reads before writes.
}

// ---------------------------------------------------------------------------
// Op dispatcher over the 100-op schedule (2 layers x 50).
// ---------------------------------------------------------------------------
template<int K>
__device__ __forceinline__ void apply_op(float2& R, float2& I,
    float c0, float s0, float c1, float s1,
    float4* __restrict__ exbuf, const int tid)
{
    constexpr int layer = K / 50;
    constexpr int k = K % 50;
    constexpr int j = lop_j(k);
    if constexpr (j < 0) {
        transpose_swap<lop_tpar(k)>(R, I, exbuf, tid);
    } else {
        apply_gate<layer * 44 + j, lop_B(k)>(R, I, c0, s0, c1, s1, tid);
    }
}

template<int... Ks>
__device__ __forceinline__ void apply_all(std::integer_sequence<int, Ks...>,
    float2& R, float2& I,
    float c0, float s0, float c1, float s1,
    float4* __restrict__ exbuf, const int tid)
{
    (apply_op<Ks>(R, I, c0, s0, c1, s1, exbuf, tid), ...);
}

__device__ __forceinline__ void evolve_once(float2& R, float2& I,
    float c0, float s0, float c1, float s1,
    float4* __restrict__ exbuf, const int tid)
{
    apply_all(std::make_integer_sequence<int, 100>{}, R, I, c0, s0, c1, s1, exbuf, tid);
}

// ---------------------------------------------------------------------------
// Fused cooperative kernel: all 3 polynomial steps + final, grid.sync between.
// grid = 512 blocks x 1024 thr = 2 blocks/CU co-resident.
// ---------------------------------------------------------------------------
__global__ __launch_bounds__(1024, 8) void fused_kernel(
    const float* __restrict__ base, const float* __restrict__ uparams,
    const float* __restrict__ lcu, const float* __restrict__ pcoef,
    float2* __restrict__ acc, float2* __restrict__ pA,
    float2* __restrict__ pB, float2* __restrict__ pC,
    float* __restrict__ out)
{
    __shared__ float4 exbuf[2048];          // 32 KB dbuf
    __shared__ float red[16];
    cg::grid_group grid = cg::this_grid();

    const int b = blockIdx.x >> 3;
    const int t = blockIdx.x & 7;
    const int tid = threadIdx.x;
    const int lane = tid & 63;

    // trig once for all 3 steps (angles identical per (b,t))
    const float* __restrict__ th_row = uparams + (size_t)(b * NT + t) * NROT;
    float th0 = 0.5f * th_row[lane];
    float th1 = (lane < NROT - 64) ? 0.5f * th_row[64 + lane] : 0.f;
    const float tc0 = cosf(th0), ts0 = sinf(th0);
    const float tc1 = cosf(th1), ts1 = sinf(th1);
    const float coeff = lcu[b * NT + t];

    float2 R, I;
    // ---- step 0: normalize base, evolve, write pA
    {
        const float2* b2s = (const float2*)(base + (size_t)b * DIM);
        float2 v = b2s[tid];
        float loc = v.x * v.x + v.y * v.y;
        for (int off = 32; off > 0; off >>= 1) loc += __shfl_down(loc, off, 64);
        if (lane == 0) red[tid >> 6] = loc;
        __syncthreads();
        float tot = 0.f;
#pragma unroll
        for (int w = 0; w < 16; ++w) tot += red[w];
        const float inv = rsqrtf(tot);
        R = make_float2(v.x * inv, v.y * inv);
        I = make_float2(0.f, 0.f);
        if (t == 0) {
            const float p0 = pcoef[0];
            float4* a4 = (float4*)(acc + (size_t)b * DIM);
            a4[tid] = make_float4(p0 * R.x, 0.f, p0 * R.y, 0.f);
        }
    }
    __syncthreads();
    evolve_once(R, I, tc0, ts0, tc1, ts1, exbuf, tid);
    ((float4*)(pA + ((size_t)b * NT + t) * DIM))[tid] =
        make_float4(coeff * R.x, coeff * I.x, coeff * R.y, coeff * I.y);
    grid.sync();

    // ---- step 1: reduce pA, evolve, write pB
    {
        R = make_float2(0.f, 0.f); I = make_float2(0.f, 0.f);
        for (int cc = 0; cc < NT; ++cc) {
            float4 v = ((const float4*)(pA + ((size_t)b * NT + cc) * DIM))[tid];
            R.x += v.x; I.x += v.y; R.y += v.z; I.y += v.w;
        }
        if (t == 0) {
            const float pk = pcoef[1];
            float4* a4 = (float4*)(acc + (size_t)b * DIM);
            float4 v = a4[tid];
            v.x += pk * R.x; v.y += pk * I.x; v.z += pk * R.y; v.w += pk * I.y;
            a4[tid] = v;
        }
    }
    evolve_once(R, I, tc0, ts0, tc1, ts1, exbuf, tid);
    ((float4*)(pB + ((size_t)b * NT + t) * DIM))[tid] =
        make_float4(coeff * R.x, coeff * I.x, coeff * R.y, coeff * I.y);
    grid.sync();

    // ---- step 2: reduce pB, evolve, write pC
    {
        R = make_float2(0.f, 0.f); I = make_float2(0.f, 0.f);
        for (int cc = 0; cc < NT; ++cc) {
            float4 v = ((const float4*)(pB + ((size_t)b * NT + cc) * DIM))[tid];
            R.x += v.x; I.x += v.y; R.y += v.z; I.y += v.w;
        }
        if (t == 0) {
            const float pk = pcoef[2];
            float4* a4 = (float4*)(acc + (size_t)b * DIM);
            float4 v = a4[tid];
            v.x += pk * R.x; v.y += pk * I.x; v.z += pk * R.y; v.w += pk * I.y;
            a4[tid] = v;
        }
    }
    evolve_once(R, I, tc0, ts0, tc1, ts1, exbuf, tid);
    ((float4*)(pC + ((size_t)b * NT + t) * DIM))[tid] =
        make_float4(coeff * R.x, coeff * I.x, coeff * R.y, coeff * I.y);
    grid.sync();

    // ---- final: block (b,t) writes its 256-complex slice
    if (tid < 256) {
        const int i = t * 256 + tid;
        float sr = 0.f, si = 0.f;
        for (int cc = 0; cc < NT; ++cc) {
            float2 v = pC[((size_t)b * NT + cc) * DIM + i];
            sr += v.x; si += v.y;
        }
        float sabs = 0.f;
        for (int q = 0; q < NPC; ++q) sabs += fabsf(pcoef[q]);
        const float invn = 1.0f / sabs;
        const float pk = pcoef[NPC - 1];
        float2 a = acc[(size_t)b * DIM + i];
        out[((size_t)b * DIM + i) * 2 + 0] = (a.x + pk * sr) * invn;
        out[((size_t)b * DIM + i) * 2 + 1] = (a.y + pk * si) * invn;
    }
}

// ---------------------------------------------------------------------------
// Fallback multi-launch kernels (r10-proven).
// ---------------------------------------------------------------------------
template<int MODE>
__global__ __launch_bounds__(1024, 8) void evolve_kernel(
    const void* __restrict__ src, const float* __restrict__ uparams,
    const float* __restrict__ lcu, float2* __restrict__ pout,
    const float* __restrict__ pcoef, float2* __restrict__ acc, int kprev)
{
    __shared__ float4 exbuf[2048];
    __shared__ float red[16];

    const int b = blockIdx.x >> 3;
    const int t = blockIdx.x & 7;
    const int tid = threadIdx.x;
    const int lane = tid & 63;

    const float* __restrict__ th_row = uparams + (size_t)(b * NT + t) * NROT;
    float th0 = 0.5f * th_row[lane];
    float th1 = (lane < NROT - 64) ? 0.5f * th_row[64 + lane] : 0.f;
    float tc0 = cosf(th0), ts0 = sinf(th0);
    float tc1 = cosf(th1), ts1 = sinf(th1);

    float2 R, I;
    if constexpr (MODE == 0) {
        const float2* b2s = (const float2*)((const float*)src + (size_t)b * DIM);
        float2 v = b2s[tid];
        float loc = v.x * v.x + v.y * v.y;
        for (int off = 32; off > 0; off >>= 1) loc += __shfl_down(loc, off, 64);
        if (lane == 0) red[tid >> 6] = loc;
        __syncthreads();
        float tot = 0.f;
#pragma unroll
        for (int w = 0; w < 16; ++w) tot += red[w];
        const float inv = rsqrtf(tot);
        R = make_float2(v.x * inv, v.y * inv);
        I = make_float2(0.f, 0.f);
        if (t == 0) {
            const float p0 = pcoef[0];
            float4* a4 = (float4*)(acc + (size_t)b * DIM);
            a4[tid] = make_float4(p0 * R.x, 0.f, p0 * R.y, 0.f);
        }
        __syncthreads();
    } else {
        R = make_float2(0.f, 0.f); I = make_float2(0.f, 0.f);
        const float2* s2 = (const float2*)src;
        for (int cc = 0; cc < NT; ++cc) {
            float4 v = ((const float4*)(s2 + ((size_t)b * NT + cc) * DIM))[tid];
            R.x += v.x; I.x += v.y; R.y += v.z; I.y += v.w;
        }
        if (t == 0 && kprev > 0) {
            const float pk = pcoef[kprev];
            float4* a4 = (float4*)(acc + (size_t)b * DIM);
            float4 v = a4[tid];
            v.x += pk * R.x; v.y += pk * I.x; v.z += pk * R.y; v.w += pk * I.y;
            a4[tid] = v;
        }
    }

    evolve_once(R, I, tc0, ts0, tc1, ts1, exbuf, tid);

    const float coeff = lcu[b * NT + t];
    ((float4*)(pout + ((size_t)b * NT + t) * DIM))[tid] =
        make_float4(coeff * R.x, coeff * I.x, coeff * R.y, coeff * I.y);
}

__global__ __launch_bounds__(256) void final_kernel(
    const float2* __restrict__ partial, const float* __restrict__ pcoef,
    const float2* __restrict__ acc, float* __restrict__ out)
{
    int b = blockIdx.x >> 3;
    int i = ((blockIdx.x & 7) << 8) | threadIdx.x;
    float sr = 0.f, si = 0.f;
    for (int c = 0; c < NT; ++c) {
        float2 v = partial[((size_t)b * NT + c) * DIM + i];
        sr += v.x; si += v.y;
    }
    float sabs = 0.f;
    for (int q = 0; q < NPC; ++q) sabs += fabsf(pcoef[q]);
    float invn = 1.0f / sabs;
    float pk = pcoef[NPC - 1];
    float2 a = acc[(size_t)b * DIM + i];
    out[((size_t)b * DIM + i) * 2 + 0] = (a.x + pk * sr) * invn;
    out[((size_t)b * DIM + i) * 2 + 1] = (a.y + pk * si) * invn;
}

extern "C" void kernel_launch(void* const* d_in, const int* in_sizes, int n_in,
                              void* d_out, int out_size, void* d_ws, size_t ws_size,
                              hipStream_t stream) {
    const float* base = (const float*)d_in[0];   // (64, 2048) f32
    const float* upar = (const float*)d_in[1];   // (64, 8, 88) f32
    const float* lcu  = (const float*)d_in[2];   // (64, 8) f32
    const float* pc   = (const float*)d_in[3];   // (4,) f32
    float* out = (float*)d_out;                  // (64, 2048, 2) f32

    const size_t plane = (size_t)BSZ * DIM * sizeof(float2);   // 1 MB
    char* ws = (char*)d_ws;

    float2* acc = (float2*)ws;
    float2* pA  = (float2*)(ws + plane);
    float2* pB  = (float2*)(ws + plane + (size_t)NT * plane);
    float2* pC  = (float2*)(ws + plane + (size_t)2 * NT * plane);

    bool fused_ok = false;
    if (ws_size >= (1 + 3 * (size_t)NT) * plane) {
        void* args[] = {(void*)&base, (void*)&upar, (void*)&lcu, (void*)&pc,
                        (void*)&acc, (void*)&pA, (void*)&pB, (void*)&pC, (void*)&out};
        hipError_t err = hipLaunchCooperativeKernel(
            (void*)fused_kernel, dim3(BSZ * NT), dim3(1024), args, 0, stream);
        fused_ok = (err == hipSuccess);
    }

    if (!fused_ok && ws_size >= (1 + 3 * (size_t)NT) * plane) {
        // r10-proven 4-launch path
        evolve_kernel<0><<<BSZ * NT, 1024, 0, stream>>>(base, upar, lcu, pA, pc, acc, 0);
        evolve_kernel<1><<<BSZ * NT, 1024, 0, stream>>>(pA,   upar, lcu, pB, pc, acc, 1);
        evolve_kernel<1><<<BSZ * NT, 1024, 0, stream>>>(pB,   upar, lcu, pC, pc, acc, 2);
        final_kernel<<<BSZ * 8, 256, 0, stream>>>(pC, pc, acc, out);
    } else if (!fused_ok) {
        // minimal-ws path: ping through pA only
        float2* working = (float2*)(ws + plane);          // reuse as working
        float2* pOnly   = (float2*)(ws + 2 * plane);
        evolve_kernel<0><<<BSZ * NT, 1024, 0, stream>>>(base, upar, lcu, pOnly, pc, acc, 0);
        evolve_kernel<1><<<BSZ * NT, 1024, 0, stream>>>(pOnly, upar, lcu, pOnly, pc, acc, 1);
        evolve_kernel<1><<<BSZ * NT, 1024, 0, stream>>>(pOnly, upar, lcu, pOnly, pc, acc, 2);
        final_kernel<<<BSZ * 8, 256, 0, stream>>>(pOnly, pc, acc, out);
        (void)working;
    }
}

// Round 12
// 89.584 us; speedup vs baseline: 2.4697x; 2.4697x over previous
//
#include <hip/hip_runtime.h>
#include <utility>

#define DIM 2048
#define NQ 11
#define NROT 88
#define BSZ 64
#define NT 8
#define NPC 4   // DEGREE+1

#if __has_builtin(__builtin_amdgcn_permlane16_swap)
#define HAVE_PL16 1
#else
#define HAVE_PL16 0
#endif
#if __has_builtin(__builtin_amdgcn_permlane32_swap)
#define HAVE_PL32 1
#else
#define HAVE_PL32 0
#endif

typedef float f32x2 __attribute__((ext_vector_type(2)));

// ---------------------------------------------------------------------------
// Packed-f32 helpers: v_pk_fma_f32 / v_pk_mul_f32 with wave-uniform
// coefficient broadcast as an SGPR pair {v,v} built in SALU (VOP3P allows
// one SGPR source per instruction).
// ---------------------------------------------------------------------------
__device__ __forceinline__ unsigned long long dup64(float v) {
    unsigned int b = __float_as_uint(v);
    return ((unsigned long long)b << 32) | (unsigned long long)b;
}
__device__ __forceinline__ f32x2 pk_mul_s(unsigned long long a2, f32x2 b) {
    f32x2 d;
    asm("v_pk_mul_f32 %0, %1, %2" : "=v"(d) : "s"(a2), "v"(b));
    return d;
}
__device__ __forceinline__ f32x2 pk_fma_s(unsigned long long a2, f32x2 b, f32x2 c) {
    f32x2 d;
    asm("v_pk_fma_f32 %0, %1, %2, %3" : "=v"(d) : "s"(a2), "v"(b), "v"(c));
    return d;
}

// ---------------------------------------------------------------------------
// Compile-time gate schedule. Gate G in [0,88); wire w <-> state bit 10-w.
// ---------------------------------------------------------------------------
constexpr int g_type(int G) {
    int j = G % 44;
    return (j < 11 || (j >= 22 && j < 33)) ? 0 : 1;   // 0=RY, 1=CRX
}
constexpr int g_pt(int G) {
    int j = G % 44;
    if (j < 11) return 10 - j;
    if (j < 22) { int i = 21 - j; int tw = (i + 1 == NQ) ? 0 : i + 1; return 10 - tw; }
    if (j < 33) return 10 - (j - 22);
    if (j == 33) return 1;
    int i = j - 34; int tw = (i + 10) % NQ; return 10 - tw;
}
constexpr int g_pcb(int G) {
    int j = G % 44;
    if (j >= 11 && j < 22) { int i = 21 - j; return 10 - i; }
    if (j == 33) return 0;
    if (j >= 34) { int i = j - 34; return 10 - i; }
    return -1;  // RY
}
constexpr bool use_sum_tier(int lb) {
    return (lb == 4 && HAVE_PL16) || (lb == 5 && HAVE_PL32);
}

// Transposed-layout bit map: swap state bits 2<->8, 3<->9, 5<->10 (r9-proven).
constexpr int tmap(int b) {
    if (b == 2) return 8;  if (b == 8) return 2;
    if (b == 3) return 9;  if (b == 9) return 3;
    if (b == 5) return 10; if (b == 10) return 5;
    return b;
}

// ---------------------------------------------------------------------------
// Per-layer op schedule (48 ops: 44 gates + 4 transposes), r9-proven.
// ---------------------------------------------------------------------------
constexpr int lop_j(int k) {
    if (k < 8)  return 3 + k;
    if (k == 8) return -1;
    if (k < 12) return k - 9;
    if (k == 12) return 11;
    if (k == 13) return -1;
    if (k < 22) return 12 + (k - 14);
    if (k == 22) return -1;
    if (k == 23) return 20;
    if (k == 24) return 21;
    if (k < 31) { int w[6] = {0, 1, 2, 3, 9, 10}; return 22 + w[k - 25]; }
    if (k < 36) return 33 + (k - 31);
    if (k == 36) return -1;
    if (k < 42) return 26 + (k - 37);
    return 38 + (k - 42);
}
constexpr bool lop_B(int k) {
    return (k >= 9 && k <= 12) || (k >= 23 && k <= 35);
}
constexpr int lop_tpar(int k) { return (k == 8 || k == 22) ? 0 : 1; }

// ---------------------------------------------------------------------------
// Wave-uniform trig fetch via readlane.
// ---------------------------------------------------------------------------
template<int G>
__device__ __forceinline__ void get_cs(float c0, float s0, float c1, float s1,
                                       float& c, float& s) {
    if constexpr (G < 64) {
        c = __int_as_float(__builtin_amdgcn_readlane(__float_as_int(c0), G));
        s = __int_as_float(__builtin_amdgcn_readlane(__float_as_int(s0), G));
    } else {
        c = __int_as_float(__builtin_amdgcn_readlane(__float_as_int(c1), G - 64));
        s = __int_as_float(__builtin_amdgcn_readlane(__float_as_int(s1), G - 64));
    }
}

// ---------------------------------------------------------------------------
// Lane exchange across tid bit LB (state bit LB+2) — PARTNER form.
// ---------------------------------------------------------------------------
template<int LB>
__device__ __forceinline__ float lxp(float x) {
    if constexpr (LB == 0) {
        return __int_as_float(__builtin_amdgcn_update_dpp(
            __float_as_int(x), __float_as_int(x), 0xB1, 0xF, 0xF, true)); // xor1
    } else if constexpr (LB == 1) {
        return __int_as_float(__builtin_amdgcn_update_dpp(
            __float_as_int(x), __float_as_int(x), 0x4E, 0xF, 0xF, true)); // xor2
    } else if constexpr (LB == 2) {
        return __int_as_float(__builtin_amdgcn_ds_swizzle(__float_as_int(x), 0x101F)); // xor4
    } else if constexpr (LB == 3) {
        return __int_as_float(__builtin_amdgcn_update_dpp(
            __float_as_int(x), __float_as_int(x), 0x128, 0xF, 0xF, true)); // row_ror:8 = xor8
    } else if constexpr (LB == 4) {
        return __int_as_float(__builtin_amdgcn_ds_swizzle(__float_as_int(x), 0x401F)); // xor16
    } else {
        return __shfl_xor(x, 32, 64);                                                  // xor32
    }
}

// SUM form: returns own + partner (order-immune to permlane*_swap ordering).
template<int LB>
__device__ __forceinline__ float lxsum(float x) {
#if HAVE_PL16
    if constexpr (LB == 4) {
        unsigned u = __float_as_uint(x);
        auto r = __builtin_amdgcn_permlane16_swap(u, u, false, false);
        return __uint_as_float(r[0]) + __uint_as_float(r[1]);
    }
#endif
#if HAVE_PL32
    if constexpr (LB == 5) {
        unsigned u = __float_as_uint(x);
        auto r = __builtin_amdgcn_permlane32_swap(u, u, false, false);
        return __uint_as_float(r[0]) + __uint_as_float(r[1]);
    }
#endif
    return x + lxp<LB>(x);
}

// ---------------------------------------------------------------------------
// Layout: 512 threads, thread tid holds amps a = tid*4 + (2m+e), m,e in {0,1}.
//   amp bits: 0=e, 1=m, 2..7=lane(tid 0..5), 8..10=block(tid 6..8)
// Layout B via transpose: bits (2,3,5) <-> (8,9,10).
// ---------------------------------------------------------------------------
template<int G, bool PB>
__device__ __forceinline__ void apply_gate(
    f32x2 (&R)[2], f32x2 (&I)[2],
    float c0, float s0, float c1, float s1, const int tid)
{
    constexpr int type = g_type(G);
    constexpr int pt   = PB ? tmap(g_pt(G)) : g_pt(G);
    constexpr int pcb0 = g_pcb(G);
    constexpr int pcb  = (pcb0 < 0) ? -1 : (PB ? tmap(pcb0) : pcb0);
    static_assert(pt <= 7, "block-bit target must run in transposed layout");
    float c, s;
    get_cs<G>(c0, s0, c1, s1, c, s);

    if constexpr (pt == 0) {
        // -------- component (e) pair: cross-element, scalar --------
        if constexpr (type == 0) {
#pragma unroll
            for (int m = 0; m < 2; ++m) {
                float er = R[m].x, orr = R[m].y, ei = I[m].x, oi = I[m].y;
                R[m].x = c*er - s*orr;  R[m].y = s*er + c*orr;
                I[m].x = c*ei - s*oi;   I[m].y = s*ei + c*oi;
            }
        } else if constexpr (pcb == 1) {
            float er = R[1].x, orr = R[1].y, ei = I[1].x, oi = I[1].y;
            R[1].x = c*er + s*oi;   I[1].x = c*ei - s*orr;
            R[1].y = c*orr + s*ei;  I[1].y = c*oi - s*er;
        } else {
            const bool ctrl = (tid >> (pcb - 2)) & 1;
            if (ctrl) {
#pragma unroll
                for (int m = 0; m < 2; ++m) {
                    float er = R[m].x, orr = R[m].y, ei = I[m].x, oi = I[m].y;
                    R[m].x = c*er + s*oi;   I[m].x = c*ei - s*orr;
                    R[m].y = c*orr + s*ei;  I[m].y = c*oi - s*er;
                }
            }
        }
    } else if constexpr (pt == 1) {
        // -------- slot (m) pair: uniform coeffs -> PACKED --------
        if constexpr (type == 0) {
            const unsigned long long cc = dup64(c), ss = dup64(s), nss = dup64(-s);
            f32x2 r0 = R[0], r1 = R[1], i0 = I[0], i1 = I[1];
            R[0] = pk_fma_s(cc, r0, pk_mul_s(nss, r1));
            R[1] = pk_fma_s(cc, r1, pk_mul_s(ss,  r0));
            I[0] = pk_fma_s(cc, i0, pk_mul_s(nss, i1));
            I[1] = pk_fma_s(cc, i1, pk_mul_s(ss,  i0));
        } else if constexpr (pcb == 0) {
            float lr = R[0].y, li = I[0].y, hr = R[1].y, hi = I[1].y;
            R[0].y = c*lr + s*hi;   I[0].y = c*li - s*hr;
            R[1].y = c*hr + s*li;   I[1].y = c*hi - s*lr;
        } else {
            const bool ctrl = (tid >> (pcb - 2)) & 1;
            if (ctrl) {
                const unsigned long long cc = dup64(c), ss = dup64(s), nss = dup64(-s);
                f32x2 r0 = R[0], r1 = R[1], i0 = I[0], i1 = I[1];
                R[0] = pk_fma_s(cc, r0, pk_mul_s(ss,  i1));
                I[0] = pk_fma_s(cc, i0, pk_mul_s(nss, r1));
                R[1] = pk_fma_s(cc, r1, pk_mul_s(ss,  i0));
                I[1] = pk_fma_s(cc, i1, pk_mul_s(nss, r0));
            }
        }
    } else {
        // -------- lane exchange across tid bit lb --------
        constexpr int lb = pt - 2;
        if constexpr (use_sum_tier(lb)) {
            // permlane sum tier: scalar (r9-proven)
            if constexpr (type == 0) {
                const float sg = ((tid >> lb) & 1) ? s : -s;
                const float k1 = c - sg;
#pragma unroll
                for (int m = 0; m < 2; ++m) {
                    float srx = lxsum<lb>(R[m].x), sry = lxsum<lb>(R[m].y);
                    float six = lxsum<lb>(I[m].x), siy = lxsum<lb>(I[m].y);
                    R[m].x = k1*R[m].x + sg*srx;  R[m].y = k1*R[m].y + sg*sry;
                    I[m].x = k1*I[m].x + sg*six;  I[m].y = k1*I[m].y + sg*siy;
                }
            } else if constexpr (pcb == 0) {
#pragma unroll
                for (int m = 0; m < 2; ++m) {
                    float sR = lxsum<lb>(R[m].y), sI = lxsum<lb>(I[m].y);
                    float r = R[m].y, i = I[m].y;
                    R[m].y = c*r - s*i + s*sI;
                    I[m].y = c*i + s*r - s*sR;
                }
            } else if constexpr (pcb == 1) {
                float sRx = lxsum<lb>(R[1].x), sRy = lxsum<lb>(R[1].y);
                float sIx = lxsum<lb>(I[1].x), sIy = lxsum<lb>(I[1].y);
                float rx = R[1].x, ry = R[1].y, ix = I[1].x, iy = I[1].y;
                R[1].x = c*rx - s*ix + s*sIx;  R[1].y = c*ry - s*iy + s*sIy;
                I[1].x = c*ix + s*rx - s*sRx;  I[1].y = c*iy + s*ry - s*sRy;
            } else {
                const bool ctrl = (tid >> (pcb - 2)) & 1;
                if (ctrl) {
#pragma unroll
                    for (int m = 0; m < 2; ++m) {
                        float sRx = lxsum<lb>(R[m].x), sRy = lxsum<lb>(R[m].y);
                        float sIx = lxsum<lb>(I[m].x), sIy = lxsum<lb>(I[m].y);
                        float rx = R[m].x, ry = R[m].y, ix = I[m].x, iy = I[m].y;
                        R[m].x = c*rx - s*ix + s*sIx;  R[m].y = c*ry - s*iy + s*sIy;
                        I[m].x = c*ix + s*rx - s*sRx;  I[m].y = c*iy + s*ry - s*sRy;
                    }
                }
            }
        } else {
            if constexpr (type == 0) {
                // RY lane gate: per-lane sign -> scalar (r9-proven)
                const float sg = ((tid >> lb) & 1) ? s : -s;
#pragma unroll
                for (int m = 0; m < 2; ++m) {
                    float prx = lxp<lb>(R[m].x), pry = lxp<lb>(R[m].y);
                    float pix = lxp<lb>(I[m].x), piy = lxp<lb>(I[m].y);
                    R[m].x = c*R[m].x + sg*prx;  R[m].y = c*R[m].y + sg*pry;
                    I[m].x = c*I[m].x + sg*pix;  I[m].y = c*I[m].y + sg*piy;
                }
            } else if constexpr (pcb == 0) {
#pragma unroll
                for (int m = 0; m < 2; ++m) {
                    float pry = lxp<lb>(R[m].y), piy = lxp<lb>(I[m].y);
                    R[m].y = c*R[m].y + s*piy;
                    I[m].y = c*I[m].y - s*pry;
                }
            } else if constexpr (pcb == 1) {
                // CRX, m=1 only: uniform coeffs -> PACKED
                const unsigned long long cc = dup64(c), ss = dup64(s), nss = dup64(-s);
                f32x2 pr, pi;
                pr.x = lxp<lb>(R[1].x); pr.y = lxp<lb>(R[1].y);
                pi.x = lxp<lb>(I[1].x); pi.y = lxp<lb>(I[1].y);
                R[1] = pk_fma_s(cc, R[1], pk_mul_s(ss,  pi));
                I[1] = pk_fma_s(cc, I[1], pk_mul_s(nss, pr));
            } else {
                // CRX, ctrl on tid bit: uniform coeffs -> PACKED in branch
                const bool ctrl = (tid >> (pcb - 2)) & 1;
                if (ctrl) {
                    const unsigned long long cc = dup64(c), ss = dup64(s), nss = dup64(-s);
#pragma unroll
                    for (int m = 0; m < 2; ++m) {
                        f32x2 pr, pi;
                        pr.x = lxp<lb>(R[m].x); pr.y = lxp<lb>(R[m].y);
                        pi.x = lxp<lb>(I[m].x); pi.y = lxp<lb>(I[m].y);
                        R[m] = pk_fma_s(cc, R[m], pk_mul_s(ss,  pi));
                        I[m] = pk_fma_s(cc, I[m], pk_mul_s(nss, pr));
                    }
                }
            }
        }
    }
}

// ---------------------------------------------------------------------------
// Whole-payload thread transpose: swap tid bits (0,1,3) <-> (6,7,8) via LDS.
// ---------------------------------------------------------------------------
__device__ __forceinline__ int swz(int s) { return s ^ ((s >> 7) & 7); }

template<int PAR>
__device__ __forceinline__ void transpose_swap(f32x2 (&R)[2], f32x2 (&I)[2],
                                               float4* __restrict__ exbuf, const int tid)
{
    float4* buf = exbuf + PAR * 1024;
    const int d06 = ((tid >> 0) ^ (tid >> 6)) & 1;
    const int d17 = ((tid >> 1) ^ (tid >> 7)) & 1;
    const int d38 = ((tid >> 3) ^ (tid >> 8)) & 1;
    const int q = tid ^ (d06 * 65) ^ (d17 * 130) ^ (d38 * 264);
    buf[swz(tid * 2 + 0)] = make_float4(R[0].x, R[0].y, I[0].x, I[0].y);
    buf[swz(tid * 2 + 1)] = make_float4(R[1].x, R[1].y, I[1].x, I[1].y);
    __syncthreads();
    float4 v0 = buf[swz(q * 2 + 0)];
    float4 v1 = buf[swz(q * 2 + 1)];
    R[0].x = v0.x; R[0].y = v0.y; I[0].x = v0.z; I[0].y = v0.w;
    R[1].x = v1.x; R[1].y = v1.y; I[1].x = v1.z; I[1].y = v1.w;
    // no trailing barrier: parity buffer reused 2 transposes later; the
    // intervening transpose's barrier orders those reads before writes.
}

// ---------------------------------------------------------------------------
// Op dispatcher over the 96-op schedule (2 layers x 48).
// ---------------------------------------------------------------------------
template<int K>
__device__ __forceinline__ void apply_op(
    f32x2 (&R)[2], f32x2 (&I)[2],
    float c0, float s0, float c1, float s1,
    float4* __restrict__ exbuf, const int tid)
{
    constexpr int layer = K / 48;
    constexpr int k = K % 48;
    constexpr int j = lop_j(k);
    if constexpr (j < 0) {
        transpose_swap<lop_tpar(k)>(R, I, exbuf, tid);
    } else {
        apply_gate<layer * 44 + j, lop_B(k)>(R, I, c0, s0, c1, s1, tid);
    }
}

template<int... Ks>
__device__ __forceinline__ void apply_all(std::integer_sequence<int, Ks...>,
    f32x2 (&R)[2], f32x2 (&I)[2],
    float c0, float s0, float c1, float s1,
    float4* __restrict__ exbuf, const int tid)
{
    (apply_op<Ks>(R, I, c0, s0, c1, s1, exbuf, tid), ...);
}

// ---------------------------------------------------------------------------
// Evolve. MODE 0: src = base (f32 real), normalize inline, t==0 writes
// acc = pc0*base. MODE 1: src = prev partials, inline-reduce; t==0 folds
// pc[kprev]*working into acc. MODE 2: src = working (fallback path).
// ---------------------------------------------------------------------------
template<int MODE>
__global__ __launch_bounds__(512, 4) void evolve_kernel(
    const void* __restrict__ src, const float* __restrict__ uparams,
    const float* __restrict__ lcu, float2* __restrict__ pout,
    const float* __restrict__ pcoef, float2* __restrict__ acc, int kprev)
{
    __shared__ float4 exbuf[2048];          // 2 x 1024 float4 (dbuf) = 32 KB
    __shared__ float red[9];

    const int b = blockIdx.x >> 3;
    const int t = blockIdx.x & 7;
    const int tid = threadIdx.x;
    const int lane = tid & 63;

    const float* __restrict__ th_row = uparams + (size_t)(b * NT + t) * NROT;
    float th0 = 0.5f * th_row[lane];
    float th1 = (lane < NROT - 64) ? 0.5f * th_row[64 + lane] : 0.f;
    float tc0 = cosf(th0), ts0 = sinf(th0);
    float tc1 = cosf(th1), ts1 = sinf(th1);

    f32x2 R[2], I[2];
    if constexpr (MODE == 0) {
        const float4* b4 = (const float4*)((const float*)src + (size_t)b * DIM);
        float4 v = b4[tid];
        float loc = v.x*v.x + v.y*v.y + v.z*v.z + v.w*v.w;
        for (int off = 32; off > 0; off >>= 1) loc += __shfl_down(loc, off, 64);
        if ((tid & 63) == 0) red[tid >> 6] = loc;
        __syncthreads();
        if (tid == 0) { float sm = 0.f; for (int w = 0; w < 8; ++w) sm += red[w]; red[8] = sm; }
        __syncthreads();
        const float inv = rsqrtf(red[8]);
        R[0].x = v.x * inv; R[0].y = v.y * inv;
        R[1].x = v.z * inv; R[1].y = v.w * inv;
        I[0].x = 0.f; I[0].y = 0.f; I[1].x = 0.f; I[1].y = 0.f;
        if (t == 0) {
            const float p0 = pcoef[0];
            float4* a4 = (float4*)(acc + (size_t)b * DIM);
            a4[tid*2+0] = make_float4(p0*R[0].x, 0.f, p0*R[0].y, 0.f);
            a4[tid*2+1] = make_float4(p0*R[1].x, 0.f, p0*R[1].y, 0.f);
        }
    } else if constexpr (MODE == 1) {
        R[0] = (f32x2)(0.f); R[1] = (f32x2)(0.f);
        I[0] = (f32x2)(0.f); I[1] = (f32x2)(0.f);
        const float2* s2 = (const float2*)src;
        for (int cc = 0; cc < NT; ++cc) {
            const float4* p4 = (const float4*)(s2 + ((size_t)b * NT + cc) * DIM);
#pragma unroll
            for (int m = 0; m < 2; ++m) {
                float4 v = p4[tid*2+m];
                R[m].x += v.x; I[m].x += v.y; R[m].y += v.z; I[m].y += v.w;
            }
        }
        if (t == 0) {
            const float pk = pcoef[kprev];
            float4* a4 = (float4*)(acc + (size_t)b * DIM);
#pragma unroll
            for (int m = 0; m < 2; ++m) {
                float4 v = a4[tid*2+m];
                v.x += pk * R[m].x; v.y += pk * I[m].x;
                v.z += pk * R[m].y; v.w += pk * I[m].y;
                a4[tid*2+m] = v;
            }
        }
    } else {
        const float2* s2 = (const float2*)src;
        const float4* p4 = (const float4*)(s2 + (size_t)b * DIM);
#pragma unroll
        for (int m = 0; m < 2; ++m) {
            float4 v = p4[tid*2+m];
            R[m].x = v.x; I[m].x = v.y; R[m].y = v.z; I[m].y = v.w;
        }
    }

    apply_all(std::make_integer_sequence<int, 96>{}, R, I,
              tc0, ts0, tc1, ts1, exbuf, tid);

    const float coeff = lcu[b * NT + t];
    float4* o4 = (float4*)(pout + ((size_t)b * NT + t) * DIM);
#pragma unroll
    for (int m = 0; m < 2; ++m)
        o4[tid*2+m] = make_float4(coeff*R[m].x, coeff*I[m].x, coeff*R[m].y, coeff*I[m].y);
}

// ---------------------------------------------------------------------------
// Final: out = (acc + pc[NPC-1] * rowsum(partial_last)) / sum|pc|
// ---------------------------------------------------------------------------
__global__ __launch_bounds__(256) void final_kernel(
    const float2* __restrict__ partial, const float* __restrict__ pcoef,
    const float2* __restrict__ acc, float* __restrict__ out)
{
    int b = blockIdx.x >> 3;
    int i = ((blockIdx.x & 7) << 8) | threadIdx.x;
    float sr = 0.f, si = 0.f;
    for (int c = 0; c < NT; ++c) {
        float2 v = partial[((size_t)b * NT + c) * DIM + i];
        sr += v.x; si += v.y;
    }
    float sabs = 0.f;
    for (int q = 0; q < NPC; ++q) sabs += fabsf(pcoef[q]);
    float invn = 1.0f / sabs;
    float pk = pcoef[NPC - 1];
    float2 a = acc[(size_t)b * DIM + i];
    out[((size_t)b * DIM + i) * 2 + 0] = (a.x + pk * sr) * invn;
    out[((size_t)b * DIM + i) * 2 + 1] = (a.y + pk * si) * invn;
}

// ---------------------------------------------------------------------------
// Fallback path helpers (small ws): setup + explicit reduce
// ---------------------------------------------------------------------------
__global__ __launch_bounds__(256) void setup_kernel(
    const float* __restrict__ base, const float* __restrict__ pc,
    float2* __restrict__ working, float2* __restrict__ acc)
{
    int b = blockIdx.x;
    int tid = threadIdx.x;
    __shared__ float red[4];
    float ssum = 0.f;
    for (int i = tid; i < DIM; i += 256) {
        float v = base[b * DIM + i];
        ssum += v * v;
    }
    for (int off = 32; off > 0; off >>= 1) ssum += __shfl_down(ssum, off, 64);
    if ((tid & 63) == 0) red[tid >> 6] = ssum;
    __syncthreads();
    if (tid == 0) red[0] = red[0] + red[1] + red[2] + red[3];
    __syncthreads();
    float inv = rsqrtf(red[0]);
    float p0 = pc[0];
    for (int i = tid; i < DIM; i += 256) {
        float v = base[b * DIM + i] * inv;
        working[b * DIM + i] = make_float2(v, 0.f);
        acc[b * DIM + i] = make_float2(p0 * v, 0.f);
    }
}

__global__ __launch_bounds__(256) void reduce_kernel(
    const float2* __restrict__ partial, const float* __restrict__ pcoef,
    float2* __restrict__ working, float2* __restrict__ acc,
    float* __restrict__ out, int k, int last)
{
    int b = blockIdx.x >> 3;
    int i = ((blockIdx.x & 7) << 8) | threadIdx.x;
    float pk = pcoef[k];
    float sr = 0.f, si = 0.f;
    for (int c = 0; c < NT; ++c) {
        float2 v = partial[((size_t)b * NT + c) * DIM + i];
        sr += v.x; si += v.y;
    }
    working[b * DIM + i] = make_float2(sr, si);
    float2 a = acc[b * DIM + i];
    a.x += pk * sr; a.y += pk * si;
    acc[b * DIM + i] = a;
    if (last) {
        float sabs = 0.f;
        for (int q = 0; q < NPC; ++q) sabs += fabsf(pcoef[q]);
        float invn = 1.0f / sabs;
        out[((size_t)b * DIM + i) * 2 + 0] = a.x * invn;
        out[((size_t)b * DIM + i) * 2 + 1] = a.y * invn;
    }
}

extern "C" void kernel_launch(void* const* d_in, const int* in_sizes, int n_in,
                              void* d_out, int out_size, void* d_ws, size_t ws_size,
                              hipStream_t stream) {
    const float* base = (const float*)d_in[0];   // (64, 2048) f32
    const float* upar = (const float*)d_in[1];   // (64, 8, 88) f32
    const float* lcu  = (const float*)d_in[2];   // (64, 8) f32
    const float* pc   = (const float*)d_in[3];   // (4,) f32
    float* out = (float*)d_out;                  // (64, 2048, 2) f32

    const size_t plane = (size_t)BSZ * DIM * sizeof(float2);   // 1 MB
    char* ws = (char*)d_ws;

    if (ws_size >= (1 + 3 * (size_t)NT) * plane) {
        // fused: 4 launches (r9-proven structure)
        float2* acc = (float2*)ws;
        float2* pA  = (float2*)(ws + plane);
        float2* pB  = (float2*)(ws + plane + (size_t)NT * plane);
        float2* pC  = (float2*)(ws + plane + (size_t)2 * NT * plane);
        evolve_kernel<0><<<BSZ * NT, 512, 0, stream>>>(base, upar, lcu, pA, pc, acc, 0);
        evolve_kernel<1><<<BSZ * NT, 512, 0, stream>>>(pA,   upar, lcu, pB, pc, acc, 1);
        evolve_kernel<1><<<BSZ * NT, 512, 0, stream>>>(pB,   upar, lcu, pC, pc, acc, 2);
        final_kernel<<<BSZ * 8, 256, 0, stream>>>(pC, pc, acc, out);
    } else {
        // fallback: working + acc + one partial buffer (10 MB)
        float2* working = (float2*)ws;
        float2* acc     = (float2*)(ws + plane);
        float2* pA      = (float2*)(ws + 2 * plane);
        setup_kernel<<<BSZ, 256, 0, stream>>>(base, pc, working, acc);
        for (int k = 1; k <= NPC - 1; ++k) {
            evolve_kernel<2><<<BSZ * NT, 512, 0, stream>>>(working, upar, lcu, pA, pc, acc, 0);
            reduce_kernel<<<BSZ * 8, 256, 0, stream>>>(pA, pc, working, acc, out,
                                                       k, (k == NPC - 1) ? 1 : 0);
        }
    }
}